// Round 13
// baseline (193.550 us; speedup 1.0000x reference)
//
#include <hip/hip_runtime.h>
#include <math.h>

#define IMG_H 512
#define IMG_W 512
#define NPLANES 48            // 16 * 3
#define RAD 5
#define TAPS 11
#define CHUNK 33              // multiple of 11 -> static ring phase after unroll
#define STRIP 64              // columns per wave (one autonomous wave per strip)
#define SBUF 80               // 74 used (64 + 2*RAD), padded

typedef float v2f __attribute__((ext_vector_type(2)));

// Compiler-only fence: cross-lane LDS dependence (lane i reads what lane j
// wrote) is INVISIBLE to LLVM alias analysis — an early round failed
// correctness exactly this way. HW needs nothing: wave has one PC and
// same-wave DS ops complete in order.
#define WAVE_FENCE_WAR()  __asm__ __volatile__("" ::: "memory")
#define WAVE_FENCE_RAW()  __asm__ __volatile__("s_waitcnt lgkmcnt(0)" ::: "memory")

struct GaussW { float w[TAPS]; };

// Structure notes (evidence-driven). Ledger:
//  - Busy-cycle invariant: VALUBusy x dur ~= 44.5us-eq post-R16; ~405
//    issue-cyc (~200 insts) per wave-row-step vs ~110 math insts.
//  - OCCUPANCY LEVER CLOSED: R16 (reg slim), R17 (768 blk = 3/CU: 92us,
//    tail theory refuted), R18 (VGPR 40 + LDS-fit-6 + (256,8): still 44%)
//    all pinned at 4 waves/SIMD — unified VGPR+AGPR footprint sits in the
//    (64,128] HW allocation band and source can't push it under 64.
//  - R19 (this): cut the ~90 overhead insts/row in load_regs. Clamp col
//    ONCE (row-invariant per-lane offset, always-safe address) ->
//    unconditional loads + v_cndmask zeroing with masks in SGPR pairs;
//    no exec-dance, no per-row zero-init, no separate tail pointer chain
//    (tail = same row base, clamped offset precomputed). Wave-uniform
//    r-guard stays scalar. Single variable on the R16 base (66.5us best).
//  - R2/R7: reg cap below footprint spills (WRITE_SIZE 48KB -> 200+MB).
//    WRITE_SIZE is the standing tripwire.
//  - R8/R9: full straight-line unroll of the row loop -> spill. Keep the
//    `for kk` + 11-row `#pragma unroll` body EXACTLY.
//  - R14: float4 staging doubled LDS read bytes/tap -> LDS-bound (188us).
//    (a,b) float2 staging stays. R18: float2 xq ring bought nothing; rq
//    stays in regs, rx stays b32 in LDS (R16 layout).
//  - R10..R13: finalize-fold dead (~83us fixed graph overhead regardless
//    of dispatch count; folded tail cost ~38us in-kernel).
//  - R3: per-row block barriers lockstep. R5: one wave per 64-col strip.
//    R6: packed fp32 (v_pk_fma). R15: reorder+drain bundle regressed
//    (confounded); drain-removal-in-isolation is the next candidate if
//    this round nulls.
__global__ __launch_bounds__(256, 4)
void ssim_main(const float* __restrict__ img1, const float* __restrict__ img2,
               double* __restrict__ sum_ws, GaussW gw) {
    __shared__ float2 srow[4][SBUF];       // one private (a,b) row buffer per wave
    __shared__ float  srx[4][TAPS][64];    // rx ring, one [11][64] per wave
    __shared__ float  wsum[4];

    const int tid  = threadIdx.x;
    const int wid  = tid >> 6;         // wave id 0..3
    const int lane = tid & 63;
    const int c0   = blockIdx.x * (4 * STRIP) + wid * STRIP;  // strip base col
    const int y0   = blockIdx.y * CHUNK;
    const size_t pbase = (size_t)blockIdx.z * (IMG_H * IMG_W);
    const float* p1 = img1 + pbase;
    const float* p2 = img2 + pbase;
    float2* buf  = srow[wid];
    float*  bufx = &srx[wid][0][0];

    // Row-invariant lane geometry, computed ONCE:
    //   main col (buf idx = lane):      c0-5+lane, may be < 0 at x-edge
    //   tail col (buf idx = 64+lane):   main+64,  lanes 0..9 only
    // Clamped offsets make every load address in-plane (safe), masks zero
    // the out-of-range lanes via cndmask (no exec dance, no zero-init).
    const int  colm = c0 - RAD + lane;
    const bool mok  = (colm >= 0) && (colm < IMG_W);
    const int  colc = colm < 0 ? 0 : (colm >= IMG_W ? IMG_W - 1 : colm);
    const int  colt = colm + STRIP;
    const bool tok  = (lane < 2 * RAD) && (colt < IMG_W);
    const int  coltc = colt >= IMG_W ? IMG_W - 1 : colt;

    // register rings, 11 rows deep (rx ring lives in LDS):
    //   rab = (conv_h(a), conv_h(b))      packed, 2-wide
    //   rq  = conv_h(a^2) + conv_h(b^2)   scalar, 1-wide (SSIM only needs sum)
    v2f rab[TAPS];
    float rq[TAPS];

    // prefetch registers for the next row (main col + 10-col tail)
    float pa, pb, pta, ptb;

    auto load_regs = [&](int r) {
        if (r >= 0 && r < IMG_H) {     // wave-uniform scalar guard
            const float* row1 = p1 + (size_t)r * IMG_W;
            const float* row2 = p2 + (size_t)r * IMG_W;
            float a = row1[colc], b = row2[colc];    // unconditional, safe
            pa = mok ? a : 0.f;                      // v_cndmask, sgpr mask
            pb = mok ? b : 0.f;
            if (lane < 2 * RAD) {                    // tail group, exec-masked
                float ta = row1[coltc], tb = row2[coltc];
                pta = tok ? ta : 0.f;
                ptb = tok ? tb : 0.f;
            }
        } else {
            pa = pb = pta = ptb = 0.f;
        }
    };

    auto store_lds = [&]() {
        WAVE_FENCE_WAR();              // don't sink this write above prior reads
        buf[lane] = make_float2(pa, pb);
        if (lane < 2 * RAD) buf[STRIP + lane] = make_float2(pta, ptb);
        WAVE_FENCE_RAW();              // don't hoist following reads above it
    };

    // packed horizontal conv: per tap 1 pk_mul + 1 mul + 2 pk_fma + 1 fma;
    // collapse the packed square accumulator once per row; rx -> LDS slot.
    auto hconv = [&](int r, int slot, v2f& oab, float& orq) {
        v2f aab = {0.f, 0.f}, asq = {0.f, 0.f};
        float ax = 0.f;
        if (r >= 0 && r < IMG_H) {     // wave-uniform: padded rows contribute zero
            #pragma unroll
            for (int d = 0; d < TAPS; ++d) {
                v2f v = *(const v2f*)&buf[lane + d];   // (a, b)
                float w = gw.w[d];
                v2f wv = {w, w};
                aab = __builtin_elementwise_fma(wv, v, aab);          // pk_fma
                v2f sq = v * v;                                       // pk_mul
                asq = __builtin_elementwise_fma(wv, sq, asq);         // pk_fma
                ax  = fmaf(w, v.x * v.y, ax);                         // mul+fma
            }
        }
        oab = aab;
        orq = asq.x + asq.y;           // conv_h(a^2)+conv_h(b^2), 1-wide
        bufx[slot * 64 + lane] = ax;   // rx ring slot in LDS (same-lane dep)
    };

    // ---- prologue: h-rows 0..9 (global rows y0-5 .. y0+4) -> ring slots 0..9
    load_regs(y0 - RAD);
    #pragma unroll
    for (int k = 0; k < TAPS - 1; ++k) {
        const int r = y0 - RAD + k;
        store_lds();
        load_regs(r + 1);              // next row's loads in flight during hconv
        hconv(r, k, rab[k], rq[k]);
    }

    const float C1v = 0.0001f;  // 0.01^2
    const float C2v = 0.0009f;  // 0.03^2
    float acc = 0.f;

    // ---- main: CHUNK output rows, unrolled by 11 so ring indices are static
    for (int kk = 0; kk < CHUNK; kk += TAPS) {
        #pragma unroll
        for (int j = 0; j < TAPS; ++j) {
            const int r = y0 - RAD + (TAPS - 1) + kk + j;  // global input row
            store_lds();               // publish prefetched row r
            load_regs(r + 1);          // issue loads for row r+1 NOW
            hconv(r, (j + 10) % TAPS, rab[(j + 10) % TAPS], rq[(j + 10) % TAPS]);

            const int y = y0 + kk + j; // output row
            if (y < IMG_H) {
                // vertical conv: per tap 1 pk_fma (mu) + 1 fma (q) + 1 fma (x)
                v2f mu = {0.f, 0.f};
                float s2q = 0.f, sx = 0.f;
                #pragma unroll
                for (int t = 0; t < TAPS; ++t) {
                    const int s = (j + t) % TAPS;  // static after unroll
                    float w = gw.w[t];
                    v2f wv = {w, w};
                    mu  = __builtin_elementwise_fma(wv, rab[s], mu);
                    s2q = fmaf(w, rq[s], s2q);
                    sx  = fmaf(w, bufx[s * 64 + lane], sx);  // rx from LDS
                }
                float mu1 = mu.x, mu2 = mu.y;
                float mu1sq = mu1 * mu1, mu2sq = mu2 * mu2, mu12 = mu1 * mu2;
                float musq = mu1sq + mu2sq;
                float sgs  = s2q - musq;        // sigma1^2 + sigma2^2
                float sg12 = sx - mu12;
                float num = (2.f * mu12 + C1v) * (2.f * sg12 + C2v);
                float den = (musq + C1v) * (sgs + C2v);
                acc += num * __builtin_amdgcn_rcpf(den);
            }
        }
    }

    // wave (64-lane) shuffle reduce -> block partials -> one atomic per block
    #pragma unroll
    for (int off = 32; off > 0; off >>= 1) acc += __shfl_down(acc, off, 64);
    if (lane == 0) wsum[wid] = acc;
    __syncthreads();                   // only block barrier in the kernel
    if (tid == 0) {
        double s = (double)wsum[0] + (double)wsum[1] + (double)wsum[2] + (double)wsum[3];
        atomicAdd(sum_ws, s);
    }
}

__global__ void ssim_finalize(const double* __restrict__ sum_ws, float* __restrict__ out) {
    out[0] = (float)(sum_ws[0] * (1.0 / (double)(16.0 * 3.0 * 512.0 * 512.0)));
}

extern "C" void kernel_launch(void* const* d_in, const int* in_sizes, int n_in,
                              void* d_out, int out_size, void* d_ws, size_t ws_size,
                              hipStream_t stream) {
    const float* img1 = (const float*)d_in[0];
    const float* img2 = (const float*)d_in[1];
    float* out = (float*)d_out;
    double* ws = (double*)d_ws;

    // d_ws is poisoned 0xAA before every launch — zero the accumulator (async, capture-safe)
    hipMemsetAsync(ws, 0, sizeof(double), stream);

    // Gaussian weights computed on host in double, passed via kernarg (SGPRs)
    GaussW gw;
    double g[TAPS], s = 0.0;
    for (int i = 0; i < TAPS; ++i) {
        double x = (double)(i - TAPS / 2);
        g[i] = exp(-(x * x) / (2.0 * 1.5 * 1.5));
        s += g[i];
    }
    for (int i = 0; i < TAPS; ++i) gw.w[i] = (float)(g[i] / s);

    // 2 x 16 x 48 = 1536 blocks; each block = 4 autonomous 64-col wave strips
    dim3 grid(IMG_W / (4 * STRIP), (IMG_H + CHUNK - 1) / CHUNK, NPLANES);
    ssim_main<<<grid, 256, 0, stream>>>(img1, img2, ws, gw);
    ssim_finalize<<<1, 1, 0, stream>>>(ws, out);
}

// Round 14
// 151.582 us; speedup vs baseline: 1.2769x; 1.2769x over previous
//
#include <hip/hip_runtime.h>
#include <math.h>

#define IMG_H 512
#define IMG_W 512
#define NPLANES 48            // 16 * 3
#define RAD 5
#define TAPS 11
#define CHUNK 33              // multiple of 11 -> static ring phase after unroll
#define STRIP 64              // columns per wave (one autonomous wave per strip)
#define SBUF 80               // 74 used (64 + 2*RAD), padded

typedef float v2f __attribute__((ext_vector_type(2)));

// Compiler-only fences: cross-lane LDS dependence (lane i reads what lane j
// wrote) is INVISIBLE to LLVM alias analysis — an early round failed
// correctness exactly this way (reads hoisted above writes). The HW needs
// nothing: a wave has one PC and same-wave DS ops execute IN ORDER in the
// DS pipe, so a later ds_read of a just-written address is coherent without
// any waitcnt (the compiler still auto-inserts lgkmcnt before USES of read
// data). R20: the old RAW fence was a hard `s_waitcnt lgkmcnt(0)` drain per
// staged row (44/strip) — removed in isolation here; drain-free form's
// correctness was already HW-proven by R15 (passed, absmax 0.0).
#define WAVE_FENCE_WAR()  __asm__ __volatile__("" ::: "memory")
#define WAVE_FENCE_RAW()  __asm__ __volatile__("" ::: "memory")

struct GaussW { float w[TAPS]; };

// Structure notes (evidence-driven). Ledger:
//  - Busy-cycle invariant: VALUBusy x dur ~= 44.5us-eq for EVERY non-spilled
//    variant since R16 (R16: 44.5, R18: 44.3 @68us, R19: 44.3 @104us).
//    Wave64 VALU = 2 issue-cyc on SIMD-32 -> ~111 math insts/row-step
//    ~= 222 cyc: the busy product is mostly irreducible math. dur = 44.5 /
//    VALUBusy at fixed 4 waves/SIMD; the only lever left is stall.
//  - OCCUPANCY CLOSED: R16 (reg slim), R17 (3 blk/CU: refuted tail), R18
//    (VGPR 32 + LDS-fit + (256,8): still 44%) — unified VGPR+AGPR footprint
//    sits in the (64,128] HW band; source can't reach the 64-reg step.
//  - ADDRESSING CLOSED: R19 clamp+cndmask rewrite: busy product UNCHANGED,
//    stalls worse (104us). load_regs was not the overhead.
//  - R20 (this): remove the per-row lgkmcnt(0) drain IN ISOLATION on the
//    R16 base (66.5us session best). R15 proved drain-free correctness but
//    bundled a body-reorder + prefetch-2 (85us, confounded). If null, the
//    remaining stall is unhideable memory latency at 4 waves -> R16 config
//    is the ceiling.
//  - R2/R7: reg cap below footprint spills (WRITE_SIZE 48KB -> 200+MB).
//  - R8/R9: full straight-line unroll of the row loop -> spill. Keep the
//    `for kk` + 11-row `#pragma unroll` body EXACTLY.
//  - R14: float4 staging -> LDS-bound (188us). (a,b) float2 staging stays.
//    R18: float2 (rx,rq) LDS ring null; rq stays in regs (R16 layout).
//  - R10..R13: finalize-fold dead (~83us fixed graph overhead regardless of
//    dispatch count; folded tail cost ~38us in-kernel).
//  - R3: per-row block barriers lockstep. R5: one wave per 64-col strip.
//    R6: packed fp32 (v_pk_fma).
__global__ __launch_bounds__(256, 6)
void ssim_main(const float* __restrict__ img1, const float* __restrict__ img2,
               double* __restrict__ sum_ws, GaussW gw) {
    __shared__ float2 srow[4][SBUF];       // one private (a,b) row buffer per wave
    __shared__ float  srx[4][TAPS][64];    // rx ring, one [11][64] per wave
    __shared__ float  wsum[4];

    const int tid  = threadIdx.x;
    const int wid  = tid >> 6;         // wave id 0..3
    const int lane = tid & 63;
    const int c0   = blockIdx.x * (4 * STRIP) + wid * STRIP;  // strip base col
    const int y0   = blockIdx.y * CHUNK;
    const size_t pbase = (size_t)blockIdx.z * (IMG_H * IMG_W);
    const float* p1 = img1 + pbase;
    const float* p2 = img2 + pbase;
    float2* buf  = srow[wid];
    float*  bufx = &srx[wid][0][0];

    // register rings, 11 rows deep (rx ring lives in LDS):
    //   rab = (conv_h(a), conv_h(b))      packed, 2-wide
    //   rq  = conv_h(a^2) + conv_h(b^2)   scalar, 1-wide (SSIM only needs sum)
    v2f rab[TAPS];
    float rq[TAPS];

    // prefetch registers for the next row (main col + 10-col tail)
    float pa, pb, pta, ptb;

    auto load_regs = [&](int r) {
        pa = pb = pta = ptb = 0.f;
        if (r >= 0 && r < IMG_H) {     // wave-uniform
            const float* row1 = p1 + (size_t)r * IMG_W;
            const float* row2 = p2 + (size_t)r * IMG_W;
            int col = c0 - RAD + lane;              // buf idx = lane
            if (col >= 0 && col < IMG_W) { pa = row1[col]; pb = row2[col]; }
            if (lane < 2 * RAD) {                   // buf idx = 64+lane
                int c2 = c0 + STRIP - RAD + lane;   // cols c0+59..c0+68
                if (c2 < IMG_W) { pta = row1[c2]; ptb = row2[c2]; }
            }
        }
    };

    auto store_lds = [&]() {
        WAVE_FENCE_WAR();              // don't sink this write above prior reads
        buf[lane] = make_float2(pa, pb);
        if (lane < 2 * RAD) buf[STRIP + lane] = make_float2(pta, ptb);
        WAVE_FENCE_RAW();              // compile-order only: reads stay below
                                       // (HW DS pipe is in-order; no drain)
    };

    // packed horizontal conv: per tap 1 pk_mul + 1 mul + 2 pk_fma + 1 fma;
    // collapse the packed square accumulator once per row; rx -> LDS slot.
    auto hconv = [&](int r, int slot, v2f& oab, float& orq) {
        v2f aab = {0.f, 0.f}, asq = {0.f, 0.f};
        float ax = 0.f;
        if (r >= 0 && r < IMG_H) {     // wave-uniform: padded rows contribute zero
            #pragma unroll
            for (int d = 0; d < TAPS; ++d) {
                v2f v = *(const v2f*)&buf[lane + d];   // (a, b)
                float w = gw.w[d];
                v2f wv = {w, w};
                aab = __builtin_elementwise_fma(wv, v, aab);          // pk_fma
                v2f sq = v * v;                                       // pk_mul
                asq = __builtin_elementwise_fma(wv, sq, asq);         // pk_fma
                ax  = fmaf(w, v.x * v.y, ax);                         // mul+fma
            }
        }
        oab = aab;
        orq = asq.x + asq.y;           // conv_h(a^2)+conv_h(b^2), 1-wide
        bufx[slot * 64 + lane] = ax;   // rx ring slot in LDS (same-lane dep)
    };

    // ---- prologue: h-rows 0..9 (global rows y0-5 .. y0+4) -> ring slots 0..9
    load_regs(y0 - RAD);
    #pragma unroll
    for (int k = 0; k < TAPS - 1; ++k) {
        const int r = y0 - RAD + k;
        store_lds();
        load_regs(r + 1);              // next row's loads in flight during hconv
        hconv(r, k, rab[k], rq[k]);
    }

    const float C1v = 0.0001f;  // 0.01^2
    const float C2v = 0.0009f;  // 0.03^2
    float acc = 0.f;

    // ---- main: CHUNK output rows, unrolled by 11 so ring indices are static
    for (int kk = 0; kk < CHUNK; kk += TAPS) {
        #pragma unroll
        for (int j = 0; j < TAPS; ++j) {
            const int r = y0 - RAD + (TAPS - 1) + kk + j;  // global input row
            store_lds();               // publish prefetched row r
            load_regs(r + 1);          // issue loads for row r+1 NOW
            hconv(r, (j + 10) % TAPS, rab[(j + 10) % TAPS], rq[(j + 10) % TAPS]);

            const int y = y0 + kk + j; // output row
            if (y < IMG_H) {
                // vertical conv: per tap 1 pk_fma (mu) + 1 fma (q) + 1 fma (x)
                v2f mu = {0.f, 0.f};
                float s2q = 0.f, sx = 0.f;
                #pragma unroll
                for (int t = 0; t < TAPS; ++t) {
                    const int s = (j + t) % TAPS;  // static after unroll
                    float w = gw.w[t];
                    v2f wv = {w, w};
                    mu  = __builtin_elementwise_fma(wv, rab[s], mu);
                    s2q = fmaf(w, rq[s], s2q);
                    sx  = fmaf(w, bufx[s * 64 + lane], sx);  // rx from LDS
                }
                float mu1 = mu.x, mu2 = mu.y;
                float mu1sq = mu1 * mu1, mu2sq = mu2 * mu2, mu12 = mu1 * mu2;
                float musq = mu1sq + mu2sq;
                float sgs  = s2q - musq;        // sigma1^2 + sigma2^2
                float sg12 = sx - mu12;
                float num = (2.f * mu12 + C1v) * (2.f * sg12 + C2v);
                float den = (musq + C1v) * (sgs + C2v);
                acc += num * __builtin_amdgcn_rcpf(den);
            }
        }
    }

    // wave (64-lane) shuffle reduce -> block partials -> one atomic per block
    #pragma unroll
    for (int off = 32; off > 0; off >>= 1) acc += __shfl_down(acc, off, 64);
    if (lane == 0) wsum[wid] = acc;
    __syncthreads();                   // only block barrier in the kernel
    if (tid == 0) {
        double s = (double)wsum[0] + (double)wsum[1] + (double)wsum[2] + (double)wsum[3];
        atomicAdd(sum_ws, s);
    }
}

__global__ void ssim_finalize(const double* __restrict__ sum_ws, float* __restrict__ out) {
    out[0] = (float)(sum_ws[0] * (1.0 / (double)(16.0 * 3.0 * 512.0 * 512.0)));
}

extern "C" void kernel_launch(void* const* d_in, const int* in_sizes, int n_in,
                              void* d_out, int out_size, void* d_ws, size_t ws_size,
                              hipStream_t stream) {
    const float* img1 = (const float*)d_in[0];
    const float* img2 = (const float*)d_in[1];
    float* out = (float*)d_out;
    double* ws = (double*)d_ws;

    // d_ws is poisoned 0xAA before every launch — zero the accumulator (async, capture-safe)
    hipMemsetAsync(ws, 0, sizeof(double), stream);

    // Gaussian weights computed on host in double, passed via kernarg (SGPRs)
    GaussW gw;
    double g[TAPS], s = 0.0;
    for (int i = 0; i < TAPS; ++i) {
        double x = (double)(i - TAPS / 2);
        g[i] = exp(-(x * x) / (2.0 * 1.5 * 1.5));
        s += g[i];
    }
    for (int i = 0; i < TAPS; ++i) gw.w[i] = (float)(g[i] / s);

    // 2 x 16 x 48 = 1536 blocks; each block = 4 autonomous 64-col wave strips
    dim3 grid(IMG_W / (4 * STRIP), (IMG_H + CHUNK - 1) / CHUNK, NPLANES);
    ssim_main<<<grid, 256, 0, stream>>>(img1, img2, ws, gw);
    ssim_finalize<<<1, 1, 0, stream>>>(ws, out);
}